// Round 4
// baseline (304.740 us; speedup 1.0000x reference)
//
#include <hip/hip_runtime.h>
#include <hip/hip_fp16.h>
#include <math.h>

#define N_NODES 50000
#define N_EDGES 800000
#define FEAT 128
#define EPS_W 1e-12f

// bucket = node >> 8 : 256 nodes per bucket, 196 buckets covers 50000
#define NB_BUCKET 196
#define NBLK_AB 128          // blocks for hist/scatter passes
#define CHUNK 6250           // edges per pass block (128*6250 = 800000)
#define SCAN_N (NB_BUCKET * NBLK_AB)   // 25088
#define GEMM_BLOCKS 3125     // 50000 / 16

typedef unsigned long long u64;

// ---------- helpers ----------
__device__ __forceinline__ float selu_f(float x) {
  const float scale = 1.0507009873554805f;
  const float alpha = 1.6732632423543772f;
  return x > 0.f ? scale * x : scale * alpha * expm1f(x);
}

__device__ __forceinline__ float2 h2f2(unsigned int u) {
  __half2 h = *reinterpret_cast<__half2*>(&u);
  return __half22float2(h);
}

// ---------- GEMM body: 16 rows of A (n x 128) @ W (128 x 128) -> fp16 out ------
__device__ __forceinline__ void gemm16_half_body(
    const float* __restrict__ A, const float* __restrict__ W,
    __half* __restrict__ out, int row0, int n, float* aL /*16*128 LDS*/) {
  for (int i = threadIdx.x; i < 16 * 128; i += 256) {
    int r = row0 + (i >> 7);
    aL[i] = (r < n) ? A[row0 * 128 + i] : 0.f;
  }
  __syncthreads();
  int col = threadIdx.x & 63;
  int rg = threadIdx.x >> 6;  // 0..3
  float acc[4][2] = {};
  const float4* a4 = (const float4*)&aL[rg * 4 * 128];
#pragma unroll 8
  for (int k4 = 0; k4 < 32; ++k4) {
    float w0 = W[(4 * k4 + 0) * 128 + col];
    float w1 = W[(4 * k4 + 1) * 128 + col];
    float w2 = W[(4 * k4 + 2) * 128 + col];
    float w3 = W[(4 * k4 + 3) * 128 + col];
    float e0 = W[(4 * k4 + 0) * 128 + col + 64];
    float e1 = W[(4 * k4 + 1) * 128 + col + 64];
    float e2 = W[(4 * k4 + 2) * 128 + col + 64];
    float e3 = W[(4 * k4 + 3) * 128 + col + 64];
#pragma unroll
    for (int r = 0; r < 4; ++r) {
      float4 a = a4[r * 32 + k4];
      acc[r][0] += a.x * w0 + a.y * w1 + a.z * w2 + a.w * w3;
      acc[r][1] += a.x * e0 + a.y * e1 + a.z * e2 + a.w * e3;
    }
  }
#pragma unroll
  for (int r = 0; r < 4; ++r) {
    int row = row0 + rg * 4 + r;
    if (row < n) {
      out[(size_t)row * 128 + col]      = __float2half_rn(acc[r][0]);
      out[(size_t)row * 128 + col + 64] = __float2half_rn(acc[r][1]);
    }
  }
}

// ---------- 1. per-block bucket histograms (src & dst) -> count matrices ------
// matrices laid out [bucket][block] so the flat exclusive scan gives global
// slot bases per (bucket, block).
__global__ __launch_bounds__(256) void pass_hist(
    const int* __restrict__ src, const int* __restrict__ dst,
    int* __restrict__ dMat, int* __restrict__ sMat) {
  __shared__ int hd[NB_BUCKET], hs[NB_BUCKET];
  for (int i = threadIdx.x; i < NB_BUCKET; i += 256) { hd[i] = 0; hs[i] = 0; }
  __syncthreads();
  int blk = blockIdx.x;
  int base = blk * CHUNK;
  for (int i = threadIdx.x; i < CHUNK; i += 256) {
    int e = base + i;
    atomicAdd(&hd[dst[e] >> 8], 1);
    atomicAdd(&hs[src[e] >> 8], 1);
  }
  __syncthreads();
  for (int i = threadIdx.x; i < NB_BUCKET; i += 256) {
    dMat[i * NBLK_AB + blk] = hd[i];
    sMat[i * NBLK_AB + blk] = hs[i];
  }
}

// ---------- 2. in-place exclusive scan of the two 25088-entry matrices --------
__global__ __launch_bounds__(1024) void scan_mat(int* __restrict__ dMat,
                                                 int* __restrict__ sMat) {
  int* m = (blockIdx.x == 0) ? dMat : sMat;
  __shared__ int sh[1024];
  int t = threadIdx.x;
  const int CH = 25;  // 1024*25 = 25600 >= 25088
  int s0 = t * CH;
  int v[CH];
  int sum = 0;
#pragma unroll
  for (int j = 0; j < CH; ++j) {
    int idx = s0 + j;
    v[j] = (idx < SCAN_N) ? m[idx] : 0;
    sum += v[j];
  }
  sh[t] = sum;
  __syncthreads();
  for (int off = 1; off < 1024; off <<= 1) {
    int x = (t >= off) ? sh[t - off] : 0;
    __syncthreads();
    sh[t] += x;
    __syncthreads();
  }
  int excl = sh[t] - sum;
#pragma unroll
  for (int j = 0; j < CH; ++j) {
    int idx = s0 + j;
    if (idx < SCAN_N) { m[idx] = excl; excl += v[j]; }
  }
}

// ---------- 3. FUSED: exact-slot bucket scatter (no global atomics) || GEMM ---
// dRec: int2 { (src<<8)|dstLow, ew_bits }   sRec: u32 { srcLow<<24 | Q23(ew) }
__global__ __launch_bounds__(256) void fused_scatter_gemm(
    const int* __restrict__ src, const int* __restrict__ dst,
    const float* __restrict__ ew,
    const int* __restrict__ dMat, const int* __restrict__ sMat,
    int2* __restrict__ dRec, unsigned* __restrict__ sRec,
    const float* __restrict__ x, const float* __restrict__ W1,
    __half* __restrict__ bufG) {
  __shared__ float aL[16 * 128];
  __shared__ int curD[NB_BUCKET], curS[NB_BUCKET];
  if (blockIdx.x >= NBLK_AB) {
    gemm16_half_body(x, W1, bufG, (blockIdx.x - NBLK_AB) * 16, N_NODES, aL);
    return;
  }
  int blk = blockIdx.x;
  for (int i = threadIdx.x; i < NB_BUCKET; i += 256) {
    curD[i] = dMat[i * NBLK_AB + blk];
    curS[i] = sMat[i * NBLK_AB + blk];
  }
  __syncthreads();
  int base = blk * CHUNK;
  for (int i = threadIdx.x; i < CHUNK; i += 256) {
    int e = base + i;
    int s = src[e], d = dst[e];
    float w = ew[e];
    int pd = atomicAdd(&curD[d >> 8], 1);           // LDS atomic
    int2 r; r.x = (s << 8) | (d & 255); r.y = __float_as_int(w);
    dRec[pd] = r;
    int ps = atomicAdd(&curS[s >> 8], 1);           // LDS atomic
    unsigned q = (unsigned)__float2uint_rn(w * 8388608.0f) & 0xFFFFFFu;  // Q23
    sRec[ps] = ((unsigned)(s & 255) << 24) | q;
  }
}

// ---------- 4. per-bucket src reduction -> inv_out ----------
__global__ __launch_bounds__(256) void bucket_src_reduce(
    const unsigned* __restrict__ sRec, const int* __restrict__ sMat,
    float* __restrict__ inv_out) {
  __shared__ float wdeg[256];
  __shared__ int cnt[256];
  int b = blockIdx.x, t = threadIdx.x;
  wdeg[t] = 0.f; cnt[t] = 0;
  __syncthreads();
  int s0 = sMat[b * NBLK_AB];
  int s1 = (b == NB_BUCKET - 1) ? N_EDGES : sMat[(b + 1) * NBLK_AB];
  for (int i = s0 + t; i < s1; i += 256) {
    unsigned r = sRec[i];
    int node = r >> 24;
    float w = (float)(r & 0xFFFFFFu) * (1.0f / 8388608.0f);
    atomicAdd(&wdeg[node], w);
    atomicAdd(&cnt[node], 1);
  }
  __syncthreads();
  int nodeg = b * 256 + t;
  if (nodeg < N_NODES) {
    inv_out[nodeg] = (1.0f / sqrtf(fmaxf(wdeg[t], EPS_W))) *
                     (1.0f / sqrtf(fmaxf((float)cnt[t], 1.0f)));
  }
}

// ---------- 5. per-bucket dst build: rowptr + rank + final CSR edges ----------
__global__ __launch_bounds__(256) void bucket_dst_build(
    const int2* __restrict__ dRec, const int* __restrict__ dMat,
    const float* __restrict__ inv_out,
    int* __restrict__ rowptr, int2* __restrict__ edges) {
  __shared__ float wdeg[256];
  __shared__ int cnt[256];
  __shared__ int excl[256];
  __shared__ float invin[256];
  __shared__ int cur[256];
  int b = blockIdx.x, t = threadIdx.x;
  wdeg[t] = 0.f; cnt[t] = 0;
  __syncthreads();
  int s0 = dMat[b * NBLK_AB];
  int s1 = (b == NB_BUCKET - 1) ? N_EDGES : dMat[(b + 1) * NBLK_AB];
  for (int i = s0 + t; i < s1; i += 256) {
    int2 r = dRec[i];
    int node = r.x & 255;
    atomicAdd(&cnt[node], 1);
    atomicAdd(&wdeg[node], __int_as_float(r.y));
  }
  __syncthreads();
  // exclusive scan of per-node counts within the bucket
  int myc = cnt[t];
  excl[t] = myc;
  __syncthreads();
  for (int off = 1; off < 256; off <<= 1) {
    int x = (t >= off) ? excl[t - off] : 0;
    __syncthreads();
    excl[t] += x;
    __syncthreads();
  }
  int myexcl = excl[t] - myc;
  int nodeg = b * 256 + t;
  if (nodeg < N_NODES) rowptr[nodeg] = s0 + myexcl;
  if (b == NB_BUCKET - 1 && t == 0) rowptr[N_NODES] = N_EDGES;
  invin[t] = (1.0f / sqrtf(fmaxf(wdeg[t], EPS_W))) *
             (1.0f / sqrtf(fmaxf((float)cnt[t], 1.0f)));
  cur[t] = s0 + myexcl;
  __syncthreads();
  for (int i = s0 + t; i < s1; i += 256) {
    int2 r = dRec[i];
    int node = r.x & 255;
    int srcn = ((unsigned)r.x) >> 8;
    float w = __int_as_float(r.y);
    float c = w * inv_out[srcn] * invin[node];
    int pos = atomicAdd(&cur[node], 1);             // LDS atomic -> rank
    int2 rec; rec.x = srcn; rec.y = __float_as_int(c);
    edges[pos] = rec;
  }
}

// ---------- half-wave gather: 32 lanes cover a 128-wide fp16 row ----------
__device__ __forceinline__ float4 gather_row_half(
    const int* __restrict__ rowptr, const int2* __restrict__ edges,
    const uint2* __restrict__ xh /* row stride 32 */, int row, int sub) {
  int beg = rowptr[row], end = rowptr[row + 1];
  float4 acc = make_float4(0.f, 0.f, 0.f, 0.f);
  int e = beg;
  for (; e + 7 < end; e += 8) {
    int2 p0 = edges[e + 0], p1 = edges[e + 1], p2 = edges[e + 2], p3 = edges[e + 3];
    int2 p4 = edges[e + 4], p5 = edges[e + 5], p6 = edges[e + 6], p7 = edges[e + 7];
    uint2 q0 = xh[(size_t)p0.x * 32 + sub];
    uint2 q1 = xh[(size_t)p1.x * 32 + sub];
    uint2 q2 = xh[(size_t)p2.x * 32 + sub];
    uint2 q3 = xh[(size_t)p3.x * 32 + sub];
    uint2 q4 = xh[(size_t)p4.x * 32 + sub];
    uint2 q5 = xh[(size_t)p5.x * 32 + sub];
    uint2 q6 = xh[(size_t)p6.x * 32 + sub];
    uint2 q7 = xh[(size_t)p7.x * 32 + sub];
#define ACC_EDGE(P, Q)                                              \
    {                                                               \
      float cc = __int_as_float(P.y);                               \
      float2 lo = h2f2(Q.x);                                        \
      float2 hi = h2f2(Q.y);                                        \
      acc.x += cc * lo.x; acc.y += cc * lo.y;                       \
      acc.z += cc * hi.x; acc.w += cc * hi.y;                       \
    }
    ACC_EDGE(p0, q0) ACC_EDGE(p1, q1) ACC_EDGE(p2, q2) ACC_EDGE(p3, q3)
    ACC_EDGE(p4, q4) ACC_EDGE(p5, q5) ACC_EDGE(p6, q6) ACC_EDGE(p7, q7)
  }
  for (; e < end; ++e) {
    int2 p0 = edges[e];
    uint2 q0 = xh[(size_t)p0.x * 32 + sub];
    ACC_EDGE(p0, q0)
  }
#undef ACC_EDGE
  return acc;
}

// ---------- 6a. layer-1: spmm(fp16 g) + bias + selu + fused @W2 -> fp16 bufB ---
__global__ __launch_bounds__(256) void spmm_selu_gemm(
    const int* __restrict__ rowptr, const int2* __restrict__ edges,
    const uint2* __restrict__ g, const float* __restrict__ bias,
    const float* __restrict__ W, __half* __restrict__ out, int n) {
  __shared__ float hL[8 * 128];
  int wid = threadIdx.x >> 6, lane = threadIdx.x & 63;
  int half = lane >> 5, sub = lane & 31;
  int lrow = wid * 2 + half;                 // 0..7 within block
  int row = blockIdx.x * 8 + lrow;           // grid exact: row < n
  float4 a = gather_row_half(rowptr, edges, g, row, sub);
  float4 b = ((const float4*)bias)[sub];
  float4 h;
  h.x = selu_f(a.x + b.x);
  h.y = selu_f(a.y + b.y);
  h.z = selu_f(a.z + b.z);
  h.w = selu_f(a.w + b.w);
  ((float4*)hL)[lrow * 32 + sub] = h;
  __syncthreads();
  int col = threadIdx.x & 127;
  int rq = threadIdx.x >> 7;
  const float4* h4 = (const float4*)&hL[rq * 4 * 128];
  float acc0 = 0.f, acc1 = 0.f, acc2 = 0.f, acc3 = 0.f;
#pragma unroll 8
  for (int k4 = 0; k4 < 32; ++k4) {
    float w0 = W[(4 * k4 + 0) * 128 + col];
    float w1 = W[(4 * k4 + 1) * 128 + col];
    float w2 = W[(4 * k4 + 2) * 128 + col];
    float w3 = W[(4 * k4 + 3) * 128 + col];
    float4 h0 = h4[0 * 32 + k4];
    float4 h1 = h4[1 * 32 + k4];
    float4 h2 = h4[2 * 32 + k4];
    float4 h3 = h4[3 * 32 + k4];
    acc0 += h0.x * w0 + h0.y * w1 + h0.z * w2 + h0.w * w3;
    acc1 += h1.x * w0 + h1.y * w1 + h1.z * w2 + h1.w * w3;
    acc2 += h2.x * w0 + h2.y * w1 + h2.z * w2 + h2.w * w3;
    acc3 += h3.x * w0 + h3.y * w1 + h3.z * w2 + h3.w * w3;
  }
  size_t r0 = (size_t)(blockIdx.x * 8 + rq * 4);
  out[(r0 + 0) * 128 + col] = __float2half_rn(acc0);
  out[(r0 + 1) * 128 + col] = __float2half_rn(acc1);
  out[(r0 + 2) * 128 + col] = __float2half_rn(acc2);
  out[(r0 + 3) * 128 + col] = __float2half_rn(acc3);
}

// ---------- 6b. layer-2: spmm(fp16 bufB) + bias + selu -> fp32 output ----------
__global__ __launch_bounds__(256) void spmm_ep(
    const int* __restrict__ rowptr, const int2* __restrict__ edges,
    const uint2* __restrict__ xh, const float* __restrict__ bias,
    float* __restrict__ out, int n) {
  int wid = threadIdx.x >> 6, lane = threadIdx.x & 63;
  int half = lane >> 5, sub = lane & 31;
  int row = blockIdx.x * 8 + wid * 2 + half;   // grid exact
  float4 a = gather_row_half(rowptr, edges, xh, row, sub);
  float4 b = ((const float4*)bias)[sub];
  float4 r;
  r.x = selu_f(a.x + b.x);
  r.y = selu_f(a.y + b.y);
  r.z = selu_f(a.z + b.z);
  r.w = selu_f(a.w + b.w);
  ((float4*)out)[(size_t)row * 32 + sub] = r;
}

extern "C" void kernel_launch(void* const* d_in, const int* in_sizes, int n_in,
                              void* d_out, int out_size, void* d_ws, size_t ws_size,
                              hipStream_t stream) {
  const float* x   = (const float*)d_in[0];
  const int*   src = (const int*)d_in[1];
  const int*   dst = (const int*)d_in[2];
  const float* ew  = (const float*)d_in[3];
  const float* W1  = (const float*)d_in[4];
  const float* b1  = (const float*)d_in[5];
  const float* W2  = (const float*)d_in[6];
  const float* b2  = (const float*)d_in[7];
  float* out = (float*)d_out;

  // workspace layout (temporal aliasing: edges over sRec; dRec over bufB)
  char* ws = (char*)d_ws;
  int*   dMat    = (int*)(ws + 0);              //   100,352 B
  int*   sMat    = (int*)(ws + 100352);         //   100,352 B -> 200,704
  float* inv_out = (float*)(ws + 200704);       //   200,000 B -> 400,704
  int*   rowptr  = (int*)(ws + 400704);         //   200,004 B -> 600,708
  // union region A: sRec (3.2 MB, dead after bucket_src_reduce) / edges (6.4 MB)
  unsigned* sRec = (unsigned*)(ws + 600712);
  int2*  edges   = (int2*)(ws + 600712);        // -> 7,000,712
  __half* bufG   = (__half*)(ws + 7000720);     // 12.8 MB -> 19,800,720
  // union region B: dRec (6.4 MB, dead before spmm_selu_gemm writes bufB)
  int2*  dRec    = (int2*)(ws + 19800720);
  __half* bufB   = (__half*)(ws + 19800720);    // 12.8 MB -> 32,600,720

  // 1. bucket histograms (src & dst) — LDS atomics only
  pass_hist<<<NBLK_AB, 256, 0, stream>>>(src, dst, dMat, sMat);
  // 2. exclusive scan of both count matrices
  scan_mat<<<2, 1024, 0, stream>>>(dMat, sMat);
  // 3. exact-slot scatter into bucket regions || bufG = fp16(x @ W1)
  fused_scatter_gemm<<<NBLK_AB + GEMM_BLOCKS, 256, 0, stream>>>(
      src, dst, ew, dMat, sMat, dRec, sRec, x, W1, bufG);
  // 4. src-side reduction -> inv_out
  bucket_src_reduce<<<NB_BUCKET, 256, 0, stream>>>(sRec, sMat, inv_out);
  // 5. dst-side build -> rowptr + final CSR edges (src, c)
  bucket_dst_build<<<NB_BUCKET, 256, 0, stream>>>(dRec, dMat, inv_out,
                                                  rowptr, edges);

  const int RB8 = N_NODES / 8;                 // 6250 (8 rows / block, exact)

  // layer 1 + layer-2 GEMM: bufB = fp16( selu(A_hat·(x@W1) + b1) @ W2 )
  spmm_selu_gemm<<<RB8, 256, 0, stream>>>(rowptr, edges, (const uint2*)bufG,
                                          b1, W2, bufB, N_NODES);
  // layer 2: out = selu(A_hat·bufB + b2)
  spmm_ep<<<RB8, 256, 0, stream>>>(rowptr, edges, (const uint2*)bufB, b2,
                                   out, N_NODES);
}